// Round 7
// baseline (204.085 us; speedup 1.0000x reference)
//
#include <hip/hip_runtime.h>

// ---------------- types / helpers ----------------
using bf16x8 = __attribute__((ext_vector_type(8))) short;
using f32x4  = __attribute__((ext_vector_type(4))) float;

static __device__ inline unsigned short f2bf(float f) {
  unsigned int u = __float_as_uint(f);
  u += 0x7fffu + ((u >> 16) & 1u);          // round-to-nearest-even
  return (unsigned short)(u >> 16);
}
static __device__ inline unsigned int pk2(float a, float b) {
  return (unsigned int)f2bf(a) | ((unsigned int)f2bf(b) << 16);
}

// butterfly reductions across the 16-lane DPP row (row_ror 1,2,4,8)
#define ROW16_MAX(x) { \
  { int _t = __builtin_amdgcn_update_dpp(0, __float_as_int(x), 0x121, 0xf, 0xf, true); x = fmaxf(x, __int_as_float(_t)); } \
  { int _t = __builtin_amdgcn_update_dpp(0, __float_as_int(x), 0x122, 0xf, 0xf, true); x = fmaxf(x, __int_as_float(_t)); } \
  { int _t = __builtin_amdgcn_update_dpp(0, __float_as_int(x), 0x124, 0xf, 0xf, true); x = fmaxf(x, __int_as_float(_t)); } \
  { int _t = __builtin_amdgcn_update_dpp(0, __float_as_int(x), 0x128, 0xf, 0xf, true); x = fmaxf(x, __int_as_float(_t)); } }
#define ROW16_SUM(x) { \
  { int _t = __builtin_amdgcn_update_dpp(0, __float_as_int(x), 0x121, 0xf, 0xf, true); x += __int_as_float(_t); } \
  { int _t = __builtin_amdgcn_update_dpp(0, __float_as_int(x), 0x122, 0xf, 0xf, true); x += __int_as_float(_t); } \
  { int _t = __builtin_amdgcn_update_dpp(0, __float_as_int(x), 0x124, 0xf, 0xf, true); x += __int_as_float(_t); } \
  { int _t = __builtin_amdgcn_update_dpp(0, __float_as_int(x), 0x128, 0xf, 0xf, true); x += __int_as_float(_t); } }

// ---------------- kernel 0: weight prep (transpose -> bf16) ----------------
__global__ __launch_bounds__(256) void prep_kernel(
    const float* __restrict__ Wq, const float* __restrict__ Wk, const float* __restrict__ Wv,
    const float* __restrict__ Wo, const float* __restrict__ bq, const float* __restrict__ bk,
    const float* __restrict__ bv,
    unsigned short* __restrict__ Wt, unsigned short* __restrict__ Wot, float* __restrict__ bqkv)
{
  int idx = blockIdx.x * 256 + threadIdx.x;
  if (idx < 192 * 1024) {
    int n = idx >> 10, k = idx & 1023;
    const float* W = (n < 64) ? Wq : (n < 128) ? Wk : Wv;
    Wt[idx] = f2bf(W[k * 64 + (n & 63)]);
  } else if (idx < 192 * 1024 + 1024 * 64) {
    int j = idx - 192 * 1024;
    int n = j >> 6, k = j & 63;
    Wot[j] = f2bf(Wo[k * 1024 + n]);
  } else if (idx < 192 * 1024 + 1024 * 64 + 192) {
    int n = idx - (192 * 1024 + 1024 * 64);
    bqkv[n] = (n < 64) ? bq[n] : (n < 128) ? bk[n - 64] : bv[n - 128];
  }
}

// ---------------- kernel 1: QKV projection, split-K=4 ----------------
// X [16384][1024] fp32, Wt [192][1024] bf16 -> qkvP[4][16384][192] fp32 partials (in d_out).
// BM=64, BN=192, BK=64, K-range 256 (4 steps). Grid 1024 = 4 blocks/CU = 16 waves/CU.
// 24 MFMA per wave per barrier-pair; per-block B traffic 98 KB (weights amortized 4x vs R6).
__global__ __launch_bounds__(256) void qkv_gemm(
    const float* __restrict__ X, const unsigned short* __restrict__ Wt,
    float* __restrict__ qkvP)
{
  __shared__ __align__(16) unsigned short As[64 * 72];
  __shared__ __align__(16) unsigned short Bs[192 * 72];
  int t = threadIdx.x, lane = t & 63, w = t >> 6;
  int col = lane & 15, quad = lane >> 4, q4 = quad * 4;
  int mt = blockIdx.x >> 2, ksl = blockIdx.x & 3;
  int m0 = mt * 64, koff = ksl * 256;
  int mg = w & 1, ng = w >> 1;               // wave: 32 rows x 96 cols
  f32x4 acc[2][6] = {};

  int rowA = t >> 2, csA = (t & 3) * 16;
  const float* srcA = X + (size_t)(m0 + rowA) * 1024 + koff + csA;

  for (int ks = 0; ks < 4; ++ks) {
    __syncthreads();
    { // stage A: 64 rows x 64 k, fp32 -> bf16 (16 floats / thread)
      const float* s = srcA + ks * 64;
      float4 f0 = *(const float4*)(s);
      float4 f1 = *(const float4*)(s + 4);
      float4 f2 = *(const float4*)(s + 8);
      float4 f3 = *(const float4*)(s + 12);
      unsigned short* d = As + rowA * 72 + csA;
      *(uint4*)(d)     = make_uint4(pk2(f0.x, f0.y), pk2(f0.z, f0.w), pk2(f1.x, f1.y), pk2(f1.z, f1.w));
      *(uint4*)(d + 8) = make_uint4(pk2(f2.x, f2.y), pk2(f2.z, f2.w), pk2(f3.x, f3.y), pk2(f3.z, f3.w));
    }
    #pragma unroll
    for (int i = 0; i < 6; ++i) { // stage B: 192 rows x 64 k (bf16 copy)
      int u = t + 256 * i;
      int rb = u >> 3, cb = u & 7;
      *(uint4*)(Bs + rb * 72 + cb * 8) =
          *(const uint4*)(Wt + (size_t)rb * 1024 + koff + ks * 64 + cb * 8);
    }
    __syncthreads();
    #pragma unroll
    for (int kk = 0; kk < 64; kk += 32) {
      int ko = kk + quad * 8;
      bf16x8 a0 = *(const bf16x8*)(As + (mg * 32 +      col) * 72 + ko);
      bf16x8 a1 = *(const bf16x8*)(As + (mg * 32 + 16 + col) * 72 + ko);
      #pragma unroll
      for (int ns = 0; ns < 6; ++ns) {
        bf16x8 b = *(const bf16x8*)(Bs + ((ng * 6 + ns) * 16 + col) * 72 + ko);
        acc[0][ns] = __builtin_amdgcn_mfma_f32_16x16x32_bf16(a0, b, acc[0][ns], 0, 0, 0);
        acc[1][ns] = __builtin_amdgcn_mfma_f32_16x16x32_bf16(a1, b, acc[1][ns], 0, 0, 0);
      }
    }
  }
  float* dst = qkvP + (size_t)ksl * 16384 * 192;
  #pragma unroll
  for (int ms = 0; ms < 2; ++ms)
    #pragma unroll
    for (int ns = 0; ns < 6; ++ns)
      #pragma unroll
      for (int r = 0; r < 4; ++r) {
        int m = m0 + mg * 32 + ms * 16 + q4 + r;
        int n = ng * 96 + ns * 16 + col;
        dst[(size_t)m * 192 + n] = acc[ms][ns][r];
      }
}

// ---------------- kernel 1b: combine partials + bias -> qkvB / vT ----------------
// Sums 4 fp32 partials, adds bias, writes qkvB [16384][128] bf16 (q|k row-major)
// and vT [8*64][2304] bf16 (v transposed, data at col 64+t; pads masked by P=0 downstream).
__global__ __launch_bounds__(256) void qkv_combine(
    const float* __restrict__ qkvP, const float* __restrict__ bqkv,
    unsigned short* __restrict__ qkvB, unsigned short* __restrict__ vT)
{
  __shared__ __align__(16) unsigned short Vl[64 * 72];
  int t = threadIdx.x;
  int m0 = blockIdx.x * 64;
  int b = m0 >> 11, i0l = m0 & 2047;
  const size_t PS = (size_t)16384 * 192;

  { // q|k: 64 rows x 128 cols
    int row = t >> 2, cs = (t & 3) * 32;
    const float* p = qkvP + (size_t)(m0 + row) * 192 + cs;
    unsigned int outp[16];
    #pragma unroll
    for (int g = 0; g < 8; ++g) {
      float4 s0 = *(const float4*)(p + g * 4);
      float4 s1 = *(const float4*)(p + PS + g * 4);
      float4 s2 = *(const float4*)(p + 2 * PS + g * 4);
      float4 s3 = *(const float4*)(p + 3 * PS + g * 4);
      const float4 bb = *(const float4*)(bqkv + cs + g * 4);
      float x0 = s0.x + s1.x + s2.x + s3.x + bb.x;
      float x1 = s0.y + s1.y + s2.y + s3.y + bb.y;
      float x2 = s0.z + s1.z + s2.z + s3.z + bb.z;
      float x3 = s0.w + s1.w + s2.w + s3.w + bb.w;
      outp[g * 2]     = pk2(x0, x1);
      outp[g * 2 + 1] = pk2(x2, x3);
    }
    unsigned short* d = qkvB + (size_t)(m0 + row) * 128 + cs;
    #pragma unroll
    for (int u = 0; u < 4; ++u)
      *(uint4*)(d + u * 8) = make_uint4(outp[u*4], outp[u*4+1], outp[u*4+2], outp[u*4+3]);
  }
  { // v: 64 rows x 64 cols -> LDS (row-major bf16)
    int row = t >> 2, vs = (t & 3) * 16;
    const float* p = qkvP + (size_t)(m0 + row) * 192 + 128 + vs;
    unsigned int outp[8];
    #pragma unroll
    for (int g = 0; g < 4; ++g) {
      float4 s0 = *(const float4*)(p + g * 4);
      float4 s1 = *(const float4*)(p + PS + g * 4);
      float4 s2 = *(const float4*)(p + 2 * PS + g * 4);
      float4 s3 = *(const float4*)(p + 3 * PS + g * 4);
      const float4 bb = *(const float4*)(bqkv + 128 + vs + g * 4);
      float x0 = s0.x + s1.x + s2.x + s3.x + bb.x;
      float x1 = s0.y + s1.y + s2.y + s3.y + bb.y;
      float x2 = s0.z + s1.z + s2.z + s3.z + bb.z;
      float x3 = s0.w + s1.w + s2.w + s3.w + bb.w;
      outp[g * 2]     = pk2(x0, x1);
      outp[g * 2 + 1] = pk2(x2, x3);
    }
    unsigned short* d = Vl + row * 72 + vs;
    *(uint4*)(d)     = make_uint4(outp[0], outp[1], outp[2], outp[3]);
    *(uint4*)(d + 8) = make_uint4(outp[4], outp[5], outp[6], outp[7]);
  }
  __syncthreads();
  { // transpose out of LDS: 64 p-rows x 64 t-cols
    int p = t >> 2, ts = (t & 3) * 16;
    unsigned int outp[8];
    #pragma unroll
    for (int g = 0; g < 8; ++g) {
      unsigned short lo = Vl[(ts + g * 2) * 72 + p];
      unsigned short hi = Vl[(ts + g * 2 + 1) * 72 + p];
      outp[g] = (unsigned int)lo | ((unsigned int)hi << 16);
    }
    unsigned short* d = vT + (size_t)(b * 64 + p) * 2304 + 64 + i0l + ts;
    *(uint4*)(d)     = make_uint4(outp[0], outp[1], outp[2], outp[3]);
    *(uint4*)(d + 8) = make_uint4(outp[4], outp[5], outp[6], outp[7]);
  }
}

// ---------------- kernel 2: banded flash attention (16-row tiles, 4-way j-split) ----------------
// Exact: out-of-band exp underflows to 0; padding mask softmax-invariant.
// Grid 1024 (4 blocks/CU, 16 waves/CU). Q/K frags direct from qkvB; V frags direct
// from vT (L2). Wave par owns j-tiles {par, par+4, par+8} (zero-padded P slots).
__global__ __launch_bounds__(256) void band_attn(
    const unsigned short* __restrict__ qkvB, const unsigned short* __restrict__ vT,
    const float* __restrict__ bias, unsigned short* __restrict__ attnB)
{
  __shared__ __align__(16) unsigned short Ps[4][16 * 72];
  __shared__ float Ocomb[3][16 * 68];
  __shared__ float mx[4][16];
  __shared__ float lx[4][16];
  __shared__ float biasL[160];

  int t = threadIdx.x, lane = t & 63, par = t >> 6;
  int col = lane & 15, quad = lane >> 4, q4 = quad * 4;
  int b = blockIdx.x >> 7;
  int i0 = (blockIdx.x & 127) * 16;
  int jw = i0 - 64;
  if (t < 160) biasL[t] = bias[1969 + t];
  const unsigned short* rowbase = qkvB + ((size_t)(b << 11)) * 128;

  // Q frags (A-layout) direct from global
  const unsigned short* qr = rowbase + (size_t)(i0 + col) * 128 + quad * 8;
  bf16x8 aq0 = *(const bf16x8*)(qr);
  bf16x8 aq1 = *(const bf16x8*)(qr + 32);

  int n_w = (par == 0) ? 3 : 2;             // owned tiles: par, par+4, (par==0: 8)
  f32x4 s[3];
  #pragma unroll
  for (int gi = 0; gi < 3; ++gi) {
    if (gi < n_w) {
      int g = par + 4 * gi;
      int jb = jw + 16 * g + col;
      int jc = jb < 0 ? 0 : (jb > 2047 ? 2047 : jb);
      const unsigned short* kr = rowbase + (size_t)jc * 128 + 64 + quad * 8;
      bf16x8 kb0 = *(const bf16x8*)(kr);
      bf16x8 kb1 = *(const bf16x8*)(kr + 32);
      f32x4 z = {};
      z = __builtin_amdgcn_mfma_f32_16x16x32_bf16(aq0, kb0, z, 0, 0, 0);
      s[gi] = __builtin_amdgcn_mfma_f32_16x16x32_bf16(aq1, kb1, z, 0, 0, 0);
    }
  }
  __syncthreads();                          // biasL ready

  float mrow[4] = {-3e38f, -3e38f, -3e38f, -3e38f};
  #pragma unroll
  for (int gi = 0; gi < 3; ++gi) {
    if (gi < n_w) {
      int g = par + 4 * gi;
      int jb = jw + 16 * g + col;
      #pragma unroll
      for (int r = 0; r < 4; ++r) {
        int imj = (i0 + q4 + r) - jb;       // i - j
        bool valid = (jb >= 0) & (jb < 2048) & (imj >= -64) & (imj <= 64);
        int si = 15 + 16 * g + col - q4 - r;   // in [0,158]
        float sv = valid ? (s[gi][r] * 0.125f + biasL[si]) : -3e38f;
        s[gi][r] = sv;
        mrow[r] = fmaxf(mrow[r], sv);
      }
    }
  }
  #pragma unroll
  for (int r = 0; r < 4; ++r) ROW16_MAX(mrow[r]);
  if (col == 0) {
    #pragma unroll
    for (int r = 0; r < 4; ++r) mx[par][q4 + r] = mrow[r];
  }
  __syncthreads();
  float m4[4];
  #pragma unroll
  for (int r = 0; r < 4; ++r)
    m4[r] = fmaxf(fmaxf(mx[0][q4 + r], mx[1][q4 + r]), fmaxf(mx[2][q4 + r], mx[3][q4 + r]));

  unsigned short* Pw = &Ps[par][0];
  float lsum[4] = {0.f, 0.f, 0.f, 0.f};
  #pragma unroll
  for (int slot = 0; slot < 4; ++slot) {
    if (slot < n_w) {
      #pragma unroll
      for (int r = 0; r < 4; ++r) {
        float p = __expf(s[slot][r] - m4[r]);
        lsum[r] += p;
        Pw[(q4 + r) * 72 + slot * 16 + col] = f2bf(p);
      }
    } else {
      #pragma unroll
      for (int r = 0; r < 4; ++r) Pw[(q4 + r) * 72 + slot * 16 + col] = 0;
    }
  }
  #pragma unroll
  for (int r = 0; r < 4; ++r) ROW16_SUM(lsum[r]);
  if (col == 0) {
    #pragma unroll
    for (int r = 0; r < 4; ++r) lx[par][q4 + r] = lsum[r];
  }

  // PV: P (16x64, zero-padded slots) x V-window; V frags straight from vT (L2).
  f32x4 o[4] = {};
  #pragma unroll
  for (int kc = 0; kc < 2; ++kc) {
    bf16x8 pa = *(const bf16x8*)(Pw + col * 72 + kc * 32 + quad * 8);
    int tile_c = par + 4 * (2 * kc + (quad >> 1));
    if (tile_c > 8) tile_c = 8;             // P=0 there; any valid addr OK
    int vcol = 64 + jw + tile_c * 16 + 8 * (quad & 1);
    #pragma unroll
    for (int nt = 0; nt < 4; ++nt) {
      bf16x8 vb = *(const bf16x8*)(vT + (size_t)(b * 64 + nt * 16 + col) * 2304 + vcol);
      o[nt] = __builtin_amdgcn_mfma_f32_16x16x32_bf16(pa, vb, o[nt], 0, 0, 0);
    }
  }
  if (par != 0) {
    #pragma unroll
    for (int nt = 0; nt < 4; ++nt)
      #pragma unroll
      for (int r = 0; r < 4; ++r)
        Ocomb[par - 1][(q4 + r) * 68 + nt * 16 + col] = o[nt][r];
  }
  __syncthreads();
  if (par == 0) {
    float rl[4];
    #pragma unroll
    for (int r = 0; r < 4; ++r)
      rl[r] = 1.0f / (lsum[r] + lx[1][q4 + r] + lx[2][q4 + r] + lx[3][q4 + r]);
    #pragma unroll
    for (int nt = 0; nt < 4; ++nt)
      #pragma unroll
      for (int r = 0; r < 4; ++r) {
        float val = (o[nt][r]
                     + Ocomb[0][(q4 + r) * 68 + nt * 16 + col]
                     + Ocomb[1][(q4 + r) * 68 + nt * 16 + col]
                     + Ocomb[2][(q4 + r) * 68 + nt * 16 + col]) * rl[r];
        int arow = (b << 11) + i0 + q4 + r;
        attnB[(size_t)arow * 64 + nt * 16 + col] = f2bf(val);
      }
  }
}

// ---------------- kernel 3: output projection (streaming MFMA, no LDS/barriers) ----------------
// attnB [16384][64] bf16 @ Wot[n][k] -> out [16384][1024] fp32 + bo. Grid 2048, 32 waves/CU.
__global__ __launch_bounds__(256) void out_gemm(
    const unsigned short* __restrict__ attnB, const unsigned short* __restrict__ Wot,
    const float* __restrict__ bo, float* __restrict__ out)
{
  int t = threadIdx.x, lane = t & 63, w = t >> 6;
  int col = lane & 15, quad = lane >> 4, q4 = quad * 4;
  int m0 = (blockIdx.x >> 1) * 16;
  int n0 = (blockIdx.x & 1) * 512 + w * 128;
  const unsigned short* ar = attnB + (size_t)(m0 + col) * 64 + quad * 8;
  bf16x8 a0 = *(const bf16x8*)(ar);
  bf16x8 a1 = *(const bf16x8*)(ar + 32);
  f32x4 acc[8] = {};
  #pragma unroll
  for (int nt = 0; nt < 8; ++nt) {
    const unsigned short* br = Wot + (size_t)(n0 + nt * 16 + col) * 64 + quad * 8;
    bf16x8 b0 = *(const bf16x8*)(br);
    bf16x8 b1 = *(const bf16x8*)(br + 32);
    acc[nt] = __builtin_amdgcn_mfma_f32_16x16x32_bf16(a0, b0, acc[nt], 0, 0, 0);
    acc[nt] = __builtin_amdgcn_mfma_f32_16x16x32_bf16(a1, b1, acc[nt], 0, 0, 0);
  }
  #pragma unroll
  for (int nt = 0; nt < 8; ++nt) {
    int nn = n0 + nt * 16 + col;
    float bb = bo[nn];
    #pragma unroll
    for (int r = 0; r < 4; ++r)
      out[(size_t)(m0 + q4 + r) * 1024 + nn] = acc[nt][r] + bb;
  }
}

// ---------------- launch ----------------
extern "C" void kernel_launch(void* const* d_in, const int* in_sizes, int n_in,
                              void* d_out, int out_size, void* d_ws, size_t ws_size,
                              hipStream_t stream) {
  const float* X    = (const float*)d_in[0];
  // d_in[1] = attention_mask: per-row constant shift -> softmax-invariant, unused
  const float* Wq   = (const float*)d_in[2];
  const float* bq   = (const float*)d_in[3];
  const float* Wk   = (const float*)d_in[4];
  const float* bk   = (const float*)d_in[5];
  const float* Wv   = (const float*)d_in[6];
  const float* bv   = (const float*)d_in[7];
  const float* Wo   = (const float*)d_in[8];
  const float* bo   = (const float*)d_in[9];
  const float* bias = (const float*)d_in[10];
  float* out = (float*)d_out;
  char* ws = (char*)d_ws;
  unsigned short* qkvB = (unsigned short*)(ws);              // 16384*128*2 = 4,194,304
  unsigned short* vT   = (unsigned short*)(ws + 4194304);    // 512*2304*2  = 2,359,296
  unsigned short* attn = (unsigned short*)(ws + 6553600);    // 16384*64*2  = 2,097,152
  unsigned short* Wt   = (unsigned short*)(ws + 8650752);    // 192*1024*2  =   393,216
  unsigned short* Wot  = (unsigned short*)(ws + 9043968);    // 1024*64*2   =   131,072
  float*          bqkv = (float*)(ws + 9175040);             // 192*4
  float*          qkvP = out;   // 4*16384*192*4 = 50.3 MB partials, overwritten by out_gemm later

  prep_kernel<<<1025, 256, 0, stream>>>(Wq, Wk, Wv, Wo, bq, bk, bv, Wt, Wot, bqkv);
  qkv_gemm<<<1024, 256, 0, stream>>>(X, Wt, qkvP);
  qkv_combine<<<256, 256, 0, stream>>>(qkvP, bqkv, qkvB, vT);
  band_attn<<<1024, 256, 0, stream>>>(qkvB, vT, bias, attn);
  out_gemm<<<2048, 256, 0, stream>>>(attn, Wot, bo, out);
}